// Round 9
// baseline (673.095 us; speedup 1.0000x reference)
//
#include <hip/hip_runtime.h>
#include <hip/hip_bf16.h>
#include <hip/hip_fp16.h>

#define D 128
#define BM 32
#define BN 128
#define LDSK 64  // unpadded k-stride; bank conflicts handled by XOR granule swizzle
#define AGG_LD 136  // padded LDS row stride for fused agg tile (row stride 272 B: 16-aligned, 2-way banks)
#define SCAN_BLK 1024  // elements per scan block (256 thr x 4)

#define GLOBAL_AS __attribute__((address_space(1)))
#define LDS_AS __attribute__((address_space(3)))

typedef __attribute__((ext_vector_type(8))) __bf16 bf16x8;
typedef __attribute__((ext_vector_type(4))) float f32x4;
typedef __hip_bfloat16 bf16;

__device__ __forceinline__ float bf2f(bf16 v) { return __bfloat162float(v); }
__device__ __forceinline__ bf16 f2bf(float v) { return __float2bfloat16(v); }

// ---------------- dtype probe: are the float tensors bf16 or fp32? ----------------
// Vectorized: uint4 (16B) independent loads per thread, 8192 words total.
__global__ void probe_kernel(const unsigned short* __restrict__ w, int n, int* __restrict__ flag) {
  __shared__ int cnt[256];
  int t = threadIdx.x;
  int bad = 0;
  int lim4 = n / 8 < 1024 ? n / 8 : 1024;  // number of uint4 groups (8 words each)
  const uint4* w4 = (const uint4*)w;
  for (int i = t; i < lim4; i += 256) {
    uint4 v = w4[i];
    unsigned int ws[8] = {v.x & 0xffffu, v.x >> 16, v.y & 0xffffu, v.y >> 16,
                          v.z & 0xffffu, v.z >> 16, v.w & 0xffffu, v.w >> 16};
#pragma unroll
    for (int j = 0; j < 8; ++j) {
      float f = __uint_as_float(ws[j] << 16);
      if (!(fabsf(f) <= 4.0f)) bad++;  // catches NaN too
    }
  }
  cnt[t] = bad;
  __syncthreads();
  for (int off = 128; off > 0; off >>= 1) {
    if (t < off) cnt[t] += cnt[t + off];
    __syncthreads();
  }
  if (t == 0) flag[0] = (cnt[0] > 512) ? 1 : 0;
}

// fp32 mode only: materialize canonical bf16 copies of x and h. Vectorized x4.
__global__ void convert_kernel(const float* __restrict__ xf, const float* __restrict__ hf,
                               bf16* __restrict__ xb, bf16* __restrict__ hb,
                               const int* __restrict__ flag, int nx, int nh) {
  if (flag[0] == 0) return;
  int i = (blockIdx.x * blockDim.x + threadIdx.x) * 4;
  if (i + 3 < nx) {
    float4 v = *(const float4*)(xf + i);
    bf16 o[4] = {f2bf(v.x), f2bf(v.y), f2bf(v.z), f2bf(v.w)};
    *(ushort4*)(xb + i) = *(const ushort4*)o;
  } else {
    for (int j = 0; j < 4; ++j)
      if (i + j < nx) xb[i + j] = f2bf(xf[i + j]);
  }
  if (i + 3 < nh) {
    float4 v = *(const float4*)(hf + i);
    bf16 o[4] = {f2bf(v.x), f2bf(v.y), f2bf(v.z), f2bf(v.w)};
    *(ushort4*)(hb + i) = *(const ushort4*)o;
  } else {
    for (int j = 0; j < 4; ++j)
      if (i + j < nh) hb[i + j] = f2bf(hf[i + j]);
  }
}

// ---------------- graph preprocessing ----------------

__global__ void zero_int_kernel(int* p, int n) {
  int i = blockIdx.x * blockDim.x + threadIdx.x;
  if (i < n) p[i] = 0;
}

__global__ void count_deg_kernel(const int* __restrict__ dst, int* __restrict__ deg, int E) {
  int e = blockIdx.x * blockDim.x + threadIdx.x;
  if (e < E) atomicAdd(&deg[dst[e]], 1);
}

// phase 1: per-block sums of 1024 deg values
__global__ void scan1_kernel(const int* __restrict__ deg, int* __restrict__ bsum, int N) {
  __shared__ int lsum[256];
  int t = threadIdx.x;
  int base = blockIdx.x * SCAN_BLK + t * 4;
  int s = 0;
  if (base + 3 < N) {
    int4 v = *(const int4*)(deg + base);
    s = v.x + v.y + v.z + v.w;
  } else {
    for (int i = 0; i < 4; ++i)
      if (base + i < N) s += deg[base + i];
  }
  lsum[t] = s;
  __syncthreads();
  for (int off = 128; off > 0; off >>= 1) {
    if (t < off) lsum[t] += lsum[t + off];
    __syncthreads();
  }
  if (t == 0) bsum[blockIdx.x] = lsum[0];
}

// phase 2: exclusive scan of block sums (nb <= 256), single block
__global__ void scan2_kernel(int* __restrict__ bsum, int nb) {
  __shared__ int sh[256];
  int t = threadIdx.x;
  sh[t] = (t < nb) ? bsum[t] : 0;
  __syncthreads();
  for (int off = 1; off < 256; off <<= 1) {
    int v = sh[t];
    int add = (t >= off) ? sh[t - off] : 0;
    __syncthreads();
    sh[t] = v + add;
    __syncthreads();
  }
  if (t < nb) bsum[t] = (t == 0) ? 0 : sh[t - 1];
}

// phase 3: per-block local scan + block offset -> offs/cursor/inv_deg
__global__ void scan3_kernel(const int* __restrict__ deg, const int* __restrict__ bsum,
                             int* __restrict__ offs, int* __restrict__ cursor,
                             float* __restrict__ inv_deg, int N, int E) {
  __shared__ int lsum[256];
  int t = threadIdx.x;
  int base = blockIdx.x * SCAN_BLK + t * 4;
  int d0 = 0, d1 = 0, d2 = 0, d3 = 0;
  if (base + 3 < N) {
    int4 v = *(const int4*)(deg + base);
    d0 = v.x; d1 = v.y; d2 = v.z; d3 = v.w;
  } else {
    if (base + 0 < N) d0 = deg[base + 0];
    if (base + 1 < N) d1 = deg[base + 1];
    if (base + 2 < N) d2 = deg[base + 2];
    if (base + 3 < N) d3 = deg[base + 3];
  }
  lsum[t] = d0 + d1 + d2 + d3;
  __syncthreads();
  for (int off = 1; off < 256; off <<= 1) {
    int v = lsum[t];
    int add = (t >= off) ? lsum[t - off] : 0;
    __syncthreads();
    lsum[t] = v + add;
    __syncthreads();
  }
  int run = bsum[blockIdx.x] + ((t == 0) ? 0 : lsum[t - 1]);
  int dd[4] = {d0, d1, d2, d3};
  for (int i = 0; i < 4; ++i) {
    int idx = base + i;
    if (idx < N) {
      offs[idx] = run;
      cursor[idx] = run;
      inv_deg[idx] = 1.0f / (float)(dd[i] > 1 ? dd[i] : 1);
      run += dd[i];
    }
  }
  if (blockIdx.x == 0 && t == 0) offs[N] = E;
}

__global__ void scatter_kernel(const int* __restrict__ src, const int* __restrict__ dst,
                               int* __restrict__ cursor, int* __restrict__ esrc, int E) {
  int e = blockIdx.x * blockDim.x + threadIdx.x;
  if (e < E) {
    int pos = atomicAdd(&cursor[dst[e]], 1);
    esrc[pos] = src[e];
  }
}

// ---------------- mean aggregation (CSR gather, one wave per node) ----------------
// (standalone dual-gather only; single-matrix rh-agg is fused into gemm2)

__global__ void agg_dual_kernel(const bf16* __restrict__ fAa, const bf16* __restrict__ fAb,
                                const bf16* __restrict__ fBa, const bf16* __restrict__ fBb,
                                const int* __restrict__ flag, const int* __restrict__ esrc,
                                const int* __restrict__ offs, const float* __restrict__ inv_deg,
                                bf16* __restrict__ outA, bf16* __restrict__ outB, int N) {
  int fl = flag[0];
  const bf16* fA = fl ? fAb : fAa;
  const bf16* fB = fl ? fBb : fBa;
  int node = (int)((blockIdx.x * (size_t)blockDim.x + threadIdx.x) >> 6);
  int lane = threadIdx.x & 63;
  if (node >= N) return;
  int e0 = offs[node], e1 = offs[node + 1];
  float a0 = 0.f, a1 = 0.f, b0 = 0.f, b1 = 0.f;
  int c = lane * 2;
  for (int base = e0; base < e1; base += 64) {
    int cnt = e1 - base;
    if (cnt > 64) cnt = 64;
    int ei = base + lane;
    int idx = esrc[ei < e1 ? ei : (e1 - 1)];
    int j = 0;
    for (; j + 4 <= cnt; j += 4) {
      int s0 = __shfl(idx, j + 0, 64), s1 = __shfl(idx, j + 1, 64);
      int s2 = __shfl(idx, j + 2, 64), s3 = __shfl(idx, j + 3, 64);
      size_t r0 = (size_t)s0 * D + c, r1 = (size_t)s1 * D + c;
      size_t r2 = (size_t)s2 * D + c, r3 = (size_t)s3 * D + c;
      __hip_bfloat162 va0 = *(const __hip_bfloat162*)(fA + r0);
      __hip_bfloat162 va1 = *(const __hip_bfloat162*)(fA + r1);
      __hip_bfloat162 va2 = *(const __hip_bfloat162*)(fA + r2);
      __hip_bfloat162 va3 = *(const __hip_bfloat162*)(fA + r3);
      __hip_bfloat162 vb0 = *(const __hip_bfloat162*)(fB + r0);
      __hip_bfloat162 vb1 = *(const __hip_bfloat162*)(fB + r1);
      __hip_bfloat162 vb2 = *(const __hip_bfloat162*)(fB + r2);
      __hip_bfloat162 vb3 = *(const __hip_bfloat162*)(fB + r3);
      a0 += bf2f(va0.x) + bf2f(va1.x) + bf2f(va2.x) + bf2f(va3.x);
      a1 += bf2f(va0.y) + bf2f(va1.y) + bf2f(va2.y) + bf2f(va3.y);
      b0 += bf2f(vb0.x) + bf2f(vb1.x) + bf2f(vb2.x) + bf2f(vb3.x);
      b1 += bf2f(vb0.y) + bf2f(vb1.y) + bf2f(vb2.y) + bf2f(vb3.y);
    }
    for (; j < cnt; ++j) {
      int s = __shfl(idx, j, 64);
      size_t ro = (size_t)s * D + c;
      __hip_bfloat162 va = *(const __hip_bfloat162*)(fA + ro);
      __hip_bfloat162 vb = *(const __hip_bfloat162*)(fB + ro);
      a0 += bf2f(va.x);
      a1 += bf2f(va.y);
      b0 += bf2f(vb.x);
      b1 += bf2f(vb.y);
    }
  }
  float w = inv_deg[node];
  __hip_bfloat162 oa, ob;
  oa.x = f2bf(a0 * w);
  oa.y = f2bf(a1 * w);
  ob.x = f2bf(b0 * w);
  ob.y = f2bf(b1 * w);
  *(__hip_bfloat162*)(outA + (size_t)node * D + c) = oa;
  *(__hip_bfloat162*)(outB + (size_t)node * D + c) = ob;
}

// ---------------- weight packing: B^T layout [n][k], k = 4 blocks of 128 ----------------

__device__ __forceinline__ float loadw(const void* p, size_t idx, int fl) {
  return fl ? ((const float*)p)[idx] : bf2f(((const bf16*)p)[idx]);
}

__global__ void pack_kernel(const void* __restrict__ Wl, const void* __restrict__ Wr,
                            const void* __restrict__ b, int l, const int* __restrict__ flag,
                            bf16* __restrict__ B1p, bf16* __restrict__ B2p,
                            float* __restrict__ bs1, float* __restrict__ bs2) {
  int fl = flag[0];
  int idx = blockIdx.x * blockDim.x + threadIdx.x;
  const int SZ1 = 256 * 512;
  const int SZ2 = 128 * 512;
  if (idx < SZ1) {
    int n = idx >> 9, k = idx & 511;
    int p = k >> 7, kr = k & 127;
    int gpair = n >> 7, nc = n & 127;
    int gate = gpair * 2 + (p >> 1);
    const void* W = (p & 1) ? Wr : Wl;
    B1p[idx] = f2bf(loadw(W, (((size_t)l * 6 + gate) * D + kr) * D + nc, fl));
  } else if (idx < SZ1 + SZ2) {
    int i2 = idx - SZ1;
    int n = i2 >> 9, k = i2 & 511;
    int p = k >> 7, kr = k & 127;
    int gate = 4 + (p >> 1);
    const void* W = (p & 1) ? Wr : Wl;
    B2p[i2] = f2bf(loadw(W, (((size_t)l * 6 + gate) * D + kr) * D + n, fl));
  } else if (idx < SZ1 + SZ2 + 384) {
    int c = idx - (SZ1 + SZ2);
    if (c < 256) {
      int g0 = (c >> 7) * 2;
      int cc = c & 127;
      bs1[c] = loadw(b, ((size_t)l * 6 + g0) * D + cc, fl) +
               loadw(b, ((size_t)l * 6 + g0 + 1) * D + cc, fl);
    } else {
      int cc = c - 256;
      bs2[cc] = loadw(b, ((size_t)l * 6 + 4) * D + cc, fl) +
                loadw(b, ((size_t)l * 6 + 5) * D + cc, fl);
    }
  }
}

// ---------------- MFMA GEMM mainloop: C[32x128] = A[32x512] @ B[512x128] ----------------
// R8 2-buffer pipeline (BM=32, 40 KB dbuf LDS, 4 blocks/CU). Template LDS_SLOT: if
// a K-block (kt>>1) equals LDS_SLOT, the A-tile comes from a block-local LDS agg tile
// (AggL, plain padded [32][AGG_LD] layout) instead of global staging — used by the
// fused gemm2 whose rh-aggregation is computed in-kernel (phase 1) for its own rows.
// XOR granule swizzle: LDS granule (r, s) holds logical k-granule s^(r&7) of row r.

__device__ __forceinline__ void stage_tile(const bf16* const (&Ablk)[4],
                                           const bf16* __restrict__ Bp, int M, int row0, int col0,
                                           bf16* As, bf16* Bs, int kt, int wave, int r_rel,
                                           int pslot, bool stageA) {
  const bf16* Aptr = Ablk[kt >> 1];
  const int kr = (kt & 1) * 64;
  if (stageA) {  // A: 32 rows, 8 rows per wave-instruction, 1 per wave
    int rchunk = wave * 8;
    int r = rchunk + r_rel;
    int gsrc = pslot ^ (r & 7);
    int rg = row0 + r;
    if (rg > M - 1) rg = M - 1;  // clamp: garbage rows never stored
    const bf16* ga = Aptr + (size_t)rg * D + kr + gsrc * 8;
    bf16* la = As + rchunk * LDSK;  // wave-uniform LDS base
    __builtin_amdgcn_global_load_lds((const GLOBAL_AS unsigned int*)(const void*)ga,
                                     (LDS_AS unsigned int*)(void*)la, 16, 0, 0);
  }
#pragma unroll
  for (int i = 0; i < 4; ++i) {  // B: 128 rows
    int rchunk = wave * 32 + i * 8;
    int r = rchunk + r_rel;
    int gsrc = pslot ^ (r & 7);
    const bf16* gb = Bp + (size_t)(col0 + r) * 512 + kt * 64 + gsrc * 8;
    bf16* lb = Bs + rchunk * LDSK;
    __builtin_amdgcn_global_load_lds((const GLOBAL_AS unsigned int*)(const void*)gb,
                                     (LDS_AS unsigned int*)(void*)lb, 16, 0, 0);
  }
}

template <int LDS_SLOT>
__device__ __forceinline__ void gemm_mainloop_t(const bf16* A0, const bf16* A1, const bf16* A2,
                                                const bf16* A3, const bf16* __restrict__ Bp, int M,
                                                int row0, int col0, bf16* As, bf16* Bs,
                                                const bf16* AggL, f32x4 (&acc)[1][4]) {
  int tid = threadIdx.x;
  int wave = tid >> 6, lane = tid & 63;
  int wrow = (wave >> 1) * 16, wcol = (wave & 1) * 64;
  const bf16* Ablk[4] = {A0, A1, A2, A3};
  int r_rel = lane >> 3;  // 0..7 within the 8-row chunk
  int pslot = lane & 7;   // physical granule this lane writes
  int quad = lane >> 4, mr = lane & 15;
  const int ABUF = BM * LDSK;  // 2048 elems per buffer
  const int BBUF = BN * LDSK;  // 8192 elems per buffer

  // prologue: stage tile 0 into buffer 0
  stage_tile(Ablk, Bp, M, row0, col0, As, Bs, 0, wave, r_rel, pslot, (0 >> 1) != LDS_SLOT);
  __syncthreads();

#pragma unroll
  for (int kt = 0; kt < 8; ++kt) {
    const int cur = kt & 1;
    // prefetch next K-tile into the other buffer (overlaps with compute below)
    if (kt < 7)
      stage_tile(Ablk, Bp, M, row0, col0, As + (cur ^ 1) * ABUF, Bs + (cur ^ 1) * BBUF, kt + 1,
                 wave, r_rel, pslot, ((kt + 1) >> 1) != LDS_SLOT);
    const bf16* Asc = As + cur * ABUF;
    const bf16* Bsc = Bs + cur * BBUF;
#pragma unroll
    for (int kk = 0; kk < 2; ++kk) {
      int G = kk * 4 + quad;  // logical granule for this lane's fragment
      bf16x8 af, bfv[4];
      {
        int R = wrow + mr;
        if ((kt >> 1) == LDS_SLOT)
          af = *(const bf16x8*)(const void*)(AggL + R * AGG_LD + (kt & 1) * 64 + G * 8);
        else
          af = *(const bf16x8*)(const void*)(Asc + R * LDSK + ((G ^ (R & 7)) * 8));
      }
#pragma unroll
      for (int ni = 0; ni < 4; ++ni) {
        int R = wcol + ni * 16 + mr;
        bfv[ni] = *(const bf16x8*)(const void*)(Bsc + R * LDSK + ((G ^ (R & 7)) * 8));
      }
#pragma unroll
      for (int ni = 0; ni < 4; ++ni)
        acc[0][ni] =
            __builtin_amdgcn_mfma_f32_16x16x32_bf16(af, bfv[ni], acc[0][ni], 0, 0, 0);
    }
    // one barrier per step: waits prefetch (implicit vmcnt(0)) + protects buffer reuse
    __syncthreads();
  }
}

// GEMM1: cols 0..127 -> z = sigmoid(.) (fp16); cols 128..255 -> rh = sigmoid(.)*h (bf16)
__global__ __launch_bounds__(256) void gemm1_kernel(
    const bf16* A0, const bf16* A1a, const bf16* A1b, const bf16* A2, const bf16* A3a,
    const bf16* A3b, const int* __restrict__ flag, const bf16* __restrict__ Bp,
    const float* __restrict__ bias, __half* __restrict__ z, bf16* __restrict__ rh, int M) {
  int fl = flag[0];
  const bf16* A1 = fl ? A1b : A1a;
  const bf16* A3 = fl ? A3b : A3a;
  const bf16* hl = A3;
  __shared__ bf16 As[2 * BM * LDSK];
  __shared__ bf16 Bs[2 * BN * LDSK];
  f32x4 acc[1][4];
#pragma unroll
  for (int j = 0; j < 4; ++j) acc[0][j] = (f32x4){0.f, 0.f, 0.f, 0.f};
  int row0 = blockIdx.x * BM, col0 = blockIdx.y * BN;  // row-fastest grid: FETCH-friendly (R0)
  gemm_mainloop_t<-1>(A0, A1, A2, A3, Bp, M, row0, col0, As, Bs, nullptr, acc);
  int lane = threadIdx.x & 63, wave = threadIdx.x >> 6;
  int wrow = (wave >> 1) * 16, wcol = (wave & 1) * 64;
  int mr = lane & 15, quad = lane >> 4;
#pragma unroll
  for (int ni = 0; ni < 4; ++ni)
#pragma unroll
    for (int r = 0; r < 4; ++r) {
      int grow = row0 + wrow + quad * 4 + r;
      if (grow >= M) continue;
      int gcol = col0 + wcol + ni * 16 + mr;
      float v = acc[0][ni][r] + bias[gcol];
      float sg = 1.0f / (1.0f + __expf(-v));
      if (gcol < 128) {
        z[(size_t)grow * D + gcol] = __float2half(sg);
      } else {
        int cc = gcol - 128;
        float hv = bf2f(hl[(size_t)grow * D + cc]);
        rh[(size_t)grow * D + cc] = f2bf(sg * hv);
      }
    }
}

// GEMM2 (fused rh-agg): phase 1 gathers the block's 32 rows of mean_agg(rh) into LDS
// (same loop order as the old agg_kernel -> bitwise-identical sums); phase 2 runs the
// K-loop with kt 4-5 (the agg slot) reading A straight from that LDS tile.
// out = z*h + (1-z)*tanh(pre); out dtype per flag; bf16 shadow into nextb (fp32 mode)
__global__ __launch_bounds__(256) void gemm2_kernel(
    const bf16* A0, const bf16* A1a, const bf16* A1b, const bf16* A3,
    const bf16* A3hA, const bf16* A3hB, const int* __restrict__ flag, const bf16* __restrict__ Bp,
    const float* __restrict__ bias, const __half* __restrict__ z,
    const int* __restrict__ esrc, const int* __restrict__ offs,
    const float* __restrict__ inv_deg, void* __restrict__ outbase,
    size_t lND, bf16* __restrict__ nextb, int M) {
  int fl = flag[0];
  const bf16* A1 = fl ? A1b : A1a;
  const bf16* hl = fl ? A3hB : A3hA;
  const bf16* rhf = A3;  // rh is bf16 in both modes
  __shared__ bf16 As[2 * BM * LDSK];
  __shared__ bf16 Bs[2 * BN * LDSK];
  __shared__ bf16 AggL[BM * AGG_LD];
  int lane = threadIdx.x & 63, wave = threadIdx.x >> 6;
  int row0 = blockIdx.x * BM, col0 = 0;

  // ---- phase 1: gather mean_agg(rh) for rows row0..row0+31 (8 nodes per wave) ----
  {
    int c = lane * 2;
#pragma unroll 1
    for (int i = 0; i < 8; ++i) {
      int r = wave * 8 + i;
      int node = row0 + r;
      float a0 = 0.f, a1 = 0.f;
      if (node < M) {
        int e0 = offs[node], e1 = offs[node + 1];
        for (int base = e0; base < e1; base += 64) {
          int cnt = e1 - base;
          if (cnt > 64) cnt = 64;
          int ei = base + lane;
          int idx = esrc[ei < e1 ? ei : (e1 - 1)];
          int j = 0;
          for (; j + 8 <= cnt; j += 8) {
            int s0 = __shfl(idx, j + 0, 64), s1 = __shfl(idx, j + 1, 64);
            int s2 = __shfl(idx, j + 2, 64), s3 = __shfl(idx, j + 3, 64);
            int s4 = __shfl(idx, j + 4, 64), s5 = __shfl(idx, j + 5, 64);
            int s6 = __shfl(idx, j + 6, 64), s7 = __shfl(idx, j + 7, 64);
            __hip_bfloat162 v0 = *(const __hip_bfloat162*)(rhf + (size_t)s0 * D + c);
            __hip_bfloat162 v1 = *(const __hip_bfloat162*)(rhf + (size_t)s1 * D + c);
            __hip_bfloat162 v2 = *(const __hip_bfloat162*)(rhf + (size_t)s2 * D + c);
            __hip_bfloat162 v3 = *(const __hip_bfloat162*)(rhf + (size_t)s3 * D + c);
            __hip_bfloat162 v4 = *(const __hip_bfloat162*)(rhf + (size_t)s4 * D + c);
            __hip_bfloat162 v5 = *(const __hip_bfloat162*)(rhf + (size_t)s5 * D + c);
            __hip_bfloat162 v6 = *(const __hip_bfloat162*)(rhf + (size_t)s6 * D + c);
            __hip_bfloat162 v7 = *(const __hip_bfloat162*)(rhf + (size_t)s7 * D + c);
            a0 += bf2f(v0.x) + bf2f(v1.x) + bf2f(v2.x) + bf2f(v3.x) +
                  bf2f(v4.x) + bf2f(v5.x) + bf2f(v6.x) + bf2f(v7.x);
            a1 += bf2f(v0.y) + bf2f(v1.y) + bf2f(v2.y) + bf2f(v3.y) +
                  bf2f(v4.y) + bf2f(v5.y) + bf2f(v6.y) + bf2f(v7.y);
          }
          for (; j < cnt; ++j) {
            int s = __shfl(idx, j, 64);
            __hip_bfloat162 v = *(const __hip_bfloat162*)(rhf + (size_t)s * D + c);
            a0 += bf2f(v.x);
            a1 += bf2f(v.y);
          }
        }
        float w = inv_deg[node];
        a0 *= w;
        a1 *= w;
      }
      __hip_bfloat162 o;
      o.x = f2bf(a0);
      o.y = f2bf(a1);
      *(__hip_bfloat162*)(AggL + r * AGG_LD + c) = o;
    }
  }
  __syncthreads();

  // ---- phase 2: GEMM with kt 4-5 A-tiles from AggL ----
  f32x4 acc[1][4];
#pragma unroll
  for (int j = 0; j < 4; ++j) acc[0][j] = (f32x4){0.f, 0.f, 0.f, 0.f};
  gemm_mainloop_t<2>(A0, A1, nullptr, A3, Bp, M, row0, col0, As, Bs, AggL, acc);
  int wrow = (wave >> 1) * 16, wcol = (wave & 1) * 64;
  int mr = lane & 15, quad = lane >> 4;
#pragma unroll
  for (int ni = 0; ni < 4; ++ni)
#pragma unroll
    for (int r = 0; r < 4; ++r) {
      int grow = row0 + wrow + quad * 4 + r;
      if (grow >= M) continue;
      int gcol = col0 + wcol + ni * 16 + mr;
      float pre = acc[0][ni][r] + bias[gcol];
      float ht = tanhf(pre);
      size_t off = (size_t)grow * D + gcol;
      float zv = __half2float(z[off]);
      float hv = bf2f(hl[off]);
      float ov = zv * hv + (1.0f - zv) * ht;
      if (fl) {
        ((float*)outbase)[lND + off] = ov;
        nextb[off] = f2bf(ov);
      } else {
        ((bf16*)outbase)[lND + off] = f2bf(ov);
      }
    }
}

// ---------------- launch ----------------

extern "C" void kernel_launch(void* const* d_in, const int* in_sizes, int n_in, void* d_out,
                              int out_size, void* d_ws, size_t ws_size, hipStream_t stream) {
  const void* x = d_in[0];
  const void* h = d_in[1];
  const void* Wl = d_in[2];
  const void* Wr = d_in[3];
  const void* b = d_in[4];
  const int* src = (const int*)d_in[5];
  const int* dst = (const int*)d_in[6];

  const int NX = in_sizes[0];
  const int NH = in_sizes[1];
  const int N = NX / D;
  const int E = in_sizes[5];
  const int L = NH / NX;
  (void)n_in;
  (void)out_size;
  (void)ws_size;

  char* ws = (char*)d_ws;
  size_t off = 0;
  auto alloc = [&](size_t bytes) -> char* {
    char* p = ws + off;
    off = (off + bytes + 255) & ~(size_t)255;
    return p;
  };
  int* flag = (int*)alloc(256);
  int* deg = (int*)alloc((size_t)N * 4);
  int* offs = (int*)alloc((size_t)(N + 1) * 4);
  int* cursor = (int*)alloc((size_t)N * 4);
  float* inv_deg = (float*)alloc((size_t)N * 4);
  int* bsum = (int*)alloc(256 * 4);
  int* esrc = (int*)alloc((size_t)E * 4);
  bf16* agg_inp = (bf16*)alloc((size_t)N * D * 2);
  bf16* agg2 = (bf16*)alloc((size_t)N * D * 2);
  bf16* rh = (bf16*)alloc((size_t)N * D * 2);
  __half* z = (__half*)alloc((size_t)N * D * 2);
  bf16* B1p = (bf16*)alloc(256 * 512 * 2);
  bf16* B2p = (bf16*)alloc(128 * 512 * 2);
  float* bs1 = (float*)alloc(256 * 4);
  float* bs2 = (float*)alloc(128 * 4);
  bf16* xb = (bf16*)alloc((size_t)NX * 2);  // fp32 mode only
  bf16* hb = (bf16*)alloc((size_t)NH * 2);  // fp32 mode only

  probe_kernel<<<1, 256, 0, stream>>>((const unsigned short*)Wl, in_sizes[2], flag);
  int ncv = NX > NH ? NX : NH;
  convert_kernel<<<(ncv / 4 + 255) / 256, 256, 0, stream>>>((const float*)x, (const float*)h, xb,
                                                            hb, flag, NX, NH);

  zero_int_kernel<<<(N + 255) / 256, 256, 0, stream>>>(deg, N);
  count_deg_kernel<<<(E + 255) / 256, 256, 0, stream>>>(dst, deg, E);
  int nb = (N + SCAN_BLK - 1) / SCAN_BLK;  // 49 for N=50000; scan2 handles nb<=256
  scan1_kernel<<<nb, 256, 0, stream>>>(deg, bsum, N);
  scan2_kernel<<<1, 256, 0, stream>>>(bsum, nb);
  scan3_kernel<<<nb, 256, 0, stream>>>(deg, bsum, offs, cursor, inv_deg, N, E);
  scatter_kernel<<<(E + 255) / 256, 256, 0, stream>>>(src, dst, cursor, esrc, E);

  int mtiles = (N + BM - 1) / BM;
  const int pack_elems = 256 * 512 + 128 * 512 + 384;
  for (int l = 0; l < L; ++l) {
    const size_t lND = (size_t)l * N * D;
    const bf16* inpA = (l == 0) ? (const bf16*)x : ((const bf16*)d_out + lND - (size_t)N * D);
    const bf16* hlA = (const bf16*)h + lND;
    const bf16* hlB = hb + lND;

    pack_kernel<<<(pack_elems + 255) / 256, 256, 0, stream>>>(Wl, Wr, b, l, flag, B1p, B2p, bs1,
                                                              bs2);
    agg_dual_kernel<<<(N + 3) / 4, 256, 0, stream>>>(inpA, xb, hlA, hlB, flag, esrc, offs, inv_deg,
                                                     agg_inp, agg2, N);
    gemm1_kernel<<<dim3(mtiles, 2), 256, 0, stream>>>(agg_inp, inpA, xb, agg2, hlA, hlB, flag, B1p,
                                                      bs1, z, rh, N);
    gemm2_kernel<<<dim3(mtiles, 1), 256, 0, stream>>>(agg_inp, inpA, xb, rh, hlA, hlB, flag, B2p,
                                                      bs2, z, esrc, offs, inv_deg, d_out, lND, xb,
                                                      N);
  }
}

// Round 10
// 586.310 us; speedup vs baseline: 1.1480x; 1.1480x over previous
//
#include <hip/hip_runtime.h>
#include <hip/hip_bf16.h>
#include <hip/hip_fp16.h>

#define D 128
#define BM 32
#define BN 128
#define LDSK 64  // unpadded k-stride; bank conflicts handled by XOR granule swizzle
#define SCAN_BLK 1024  // elements per scan block (256 thr x 4)

#define GLOBAL_AS __attribute__((address_space(1)))
#define LDS_AS __attribute__((address_space(3)))

typedef __attribute__((ext_vector_type(8))) __bf16 bf16x8;
typedef __attribute__((ext_vector_type(4))) float f32x4;
typedef __hip_bfloat16 bf16;

__device__ __forceinline__ float bf2f(bf16 v) { return __bfloat162float(v); }
__device__ __forceinline__ bf16 f2bf(float v) { return __float2bfloat16(v); }
__device__ __forceinline__ float bfu(unsigned short u) {
  return __uint_as_float(((unsigned int)u) << 16);
}

// ---------------- dtype probe: are the float tensors bf16 or fp32? ----------------
// Vectorized: uint4 (16B) independent loads per thread, 8192 words total.
__global__ void probe_kernel(const unsigned short* __restrict__ w, int n, int* __restrict__ flag) {
  __shared__ int cnt[256];
  int t = threadIdx.x;
  int bad = 0;
  int lim4 = n / 8 < 1024 ? n / 8 : 1024;  // number of uint4 groups (8 words each)
  const uint4* w4 = (const uint4*)w;
  for (int i = t; i < lim4; i += 256) {
    uint4 v = w4[i];
    unsigned int ws[8] = {v.x & 0xffffu, v.x >> 16, v.y & 0xffffu, v.y >> 16,
                          v.z & 0xffffu, v.z >> 16, v.w & 0xffffu, v.w >> 16};
#pragma unroll
    for (int j = 0; j < 8; ++j) {
      float f = __uint_as_float(ws[j] << 16);
      if (!(fabsf(f) <= 4.0f)) bad++;  // catches NaN too
    }
  }
  cnt[t] = bad;
  __syncthreads();
  for (int off = 128; off > 0; off >>= 1) {
    if (t < off) cnt[t] += cnt[t + off];
    __syncthreads();
  }
  if (t == 0) flag[0] = (cnt[0] > 512) ? 1 : 0;
}

// fp32 mode only: materialize canonical bf16 copies of x and h. Vectorized x4.
__global__ void convert_kernel(const float* __restrict__ xf, const float* __restrict__ hf,
                               bf16* __restrict__ xb, bf16* __restrict__ hb,
                               const int* __restrict__ flag, int nx, int nh) {
  if (flag[0] == 0) return;
  int i = (blockIdx.x * blockDim.x + threadIdx.x) * 4;
  if (i + 3 < nx) {
    float4 v = *(const float4*)(xf + i);
    bf16 o[4] = {f2bf(v.x), f2bf(v.y), f2bf(v.z), f2bf(v.w)};
    *(ushort4*)(xb + i) = *(const ushort4*)o;
  } else {
    for (int j = 0; j < 4; ++j)
      if (i + j < nx) xb[i + j] = f2bf(xf[i + j]);
  }
  if (i + 3 < nh) {
    float4 v = *(const float4*)(hf + i);
    bf16 o[4] = {f2bf(v.x), f2bf(v.y), f2bf(v.z), f2bf(v.w)};
    *(ushort4*)(hb + i) = *(const ushort4*)o;
  } else {
    for (int j = 0; j < 4; ++j)
      if (i + j < nh) hb[i + j] = f2bf(hf[i + j]);
  }
}

// ---------------- graph preprocessing ----------------

__global__ void zero_int_kernel(int* p, int n) {
  int i = blockIdx.x * blockDim.x + threadIdx.x;
  if (i < n) p[i] = 0;
}

__global__ void count_deg_kernel(const int* __restrict__ dst, int* __restrict__ deg, int E) {
  int e = blockIdx.x * blockDim.x + threadIdx.x;
  if (e < E) atomicAdd(&deg[dst[e]], 1);
}

// phase 1: per-block sums of 1024 deg values
__global__ void scan1_kernel(const int* __restrict__ deg, int* __restrict__ bsum, int N) {
  __shared__ int lsum[256];
  int t = threadIdx.x;
  int base = blockIdx.x * SCAN_BLK + t * 4;
  int s = 0;
  if (base + 3 < N) {
    int4 v = *(const int4*)(deg + base);
    s = v.x + v.y + v.z + v.w;
  } else {
    for (int i = 0; i < 4; ++i)
      if (base + i < N) s += deg[base + i];
  }
  lsum[t] = s;
  __syncthreads();
  for (int off = 128; off > 0; off >>= 1) {
    if (t < off) lsum[t] += lsum[t + off];
    __syncthreads();
  }
  if (t == 0) bsum[blockIdx.x] = lsum[0];
}

// phase 2: exclusive scan of block sums (nb <= 256), single block
__global__ void scan2_kernel(int* __restrict__ bsum, int nb) {
  __shared__ int sh[256];
  int t = threadIdx.x;
  sh[t] = (t < nb) ? bsum[t] : 0;
  __syncthreads();
  for (int off = 1; off < 256; off <<= 1) {
    int v = sh[t];
    int add = (t >= off) ? sh[t - off] : 0;
    __syncthreads();
    sh[t] = v + add;
    __syncthreads();
  }
  if (t < nb) bsum[t] = (t == 0) ? 0 : sh[t - 1];
}

// phase 3: per-block local scan + block offset -> offs/cursor/inv_deg
__global__ void scan3_kernel(const int* __restrict__ deg, const int* __restrict__ bsum,
                             int* __restrict__ offs, int* __restrict__ cursor,
                             float* __restrict__ inv_deg, int N, int E) {
  __shared__ int lsum[256];
  int t = threadIdx.x;
  int base = blockIdx.x * SCAN_BLK + t * 4;
  int d0 = 0, d1 = 0, d2 = 0, d3 = 0;
  if (base + 3 < N) {
    int4 v = *(const int4*)(deg + base);
    d0 = v.x; d1 = v.y; d2 = v.z; d3 = v.w;
  } else {
    if (base + 0 < N) d0 = deg[base + 0];
    if (base + 1 < N) d1 = deg[base + 1];
    if (base + 2 < N) d2 = deg[base + 2];
    if (base + 3 < N) d3 = deg[base + 3];
  }
  lsum[t] = d0 + d1 + d2 + d3;
  __syncthreads();
  for (int off = 1; off < 256; off <<= 1) {
    int v = lsum[t];
    int add = (t >= off) ? lsum[t - off] : 0;
    __syncthreads();
    lsum[t] = v + add;
    __syncthreads();
  }
  int run = bsum[blockIdx.x] + ((t == 0) ? 0 : lsum[t - 1]);
  int dd[4] = {d0, d1, d2, d3};
  for (int i = 0; i < 4; ++i) {
    int idx = base + i;
    if (idx < N) {
      offs[idx] = run;
      cursor[idx] = run;
      inv_deg[idx] = 1.0f / (float)(dd[i] > 1 ? dd[i] : 1);
      run += dd[i];
    }
  }
  if (blockIdx.x == 0 && t == 0) offs[N] = E;
}

__global__ void scatter_kernel(const int* __restrict__ src, const int* __restrict__ dst,
                               int* __restrict__ cursor, int* __restrict__ esrc, int E) {
  int e = blockIdx.x * blockDim.x + threadIdx.x;
  if (e < E) {
    int pos = atomicAdd(&cursor[dst[e]], 1);
    esrc[pos] = src[e];
  }
}

// ---------------- mean aggregation (CSR gather, one wave per node) ----------------
// 8B/lane gather: lanes split into two row-slots (p = lane>>5); each vector-memory
// instruction gathers TWO rows (32 lanes x ushort4 each) -> half the gather
// instructions, shfl broadcasts, and accumulate ops vs the 4B/lane version.
// Cross-parity __shfl_xor(32) reduce at the end; lanes 0..31 write ushort4.

__global__ void agg_kernel(const bf16* __restrict__ featA, const bf16* __restrict__ featB,
                           const int* __restrict__ flag, const int* __restrict__ esrc,
                           const int* __restrict__ offs, const float* __restrict__ inv_deg,
                           bf16* __restrict__ out, int N) {
  const bf16* feat = flag[0] ? featB : featA;
  int node = (int)((blockIdx.x * (size_t)blockDim.x + threadIdx.x) >> 6);
  int lane = threadIdx.x & 63;
  if (node >= N) return;
  int e0 = offs[node], e1 = offs[node + 1];
  int p = lane >> 5;         // row slot within an edge pair
  int c4 = (lane & 31) * 4;  // 4 cols per lane
  float a0 = 0.f, a1 = 0.f, a2 = 0.f, a3 = 0.f;
  for (int base = e0; base < e1; base += 64) {
    int cnt = e1 - base;
    if (cnt > 64) cnt = 64;
    int ei = base + lane;
    int idx = esrc[ei < e1 ? ei : (e1 - 1)];
    int j = 0;
    for (; j + 8 <= cnt; j += 8) {
      int s0 = __shfl(idx, j + 0 + p, 64), s1 = __shfl(idx, j + 2 + p, 64);
      int s2 = __shfl(idx, j + 4 + p, 64), s3 = __shfl(idx, j + 6 + p, 64);
      ushort4 v0 = *(const ushort4*)(feat + (size_t)s0 * D + c4);
      ushort4 v1 = *(const ushort4*)(feat + (size_t)s1 * D + c4);
      ushort4 v2 = *(const ushort4*)(feat + (size_t)s2 * D + c4);
      ushort4 v3 = *(const ushort4*)(feat + (size_t)s3 * D + c4);
      a0 += bfu(v0.x) + bfu(v1.x) + bfu(v2.x) + bfu(v3.x);
      a1 += bfu(v0.y) + bfu(v1.y) + bfu(v2.y) + bfu(v3.y);
      a2 += bfu(v0.z) + bfu(v1.z) + bfu(v2.z) + bfu(v3.z);
      a3 += bfu(v0.w) + bfu(v1.w) + bfu(v2.w) + bfu(v3.w);
    }
    for (; j + 2 <= cnt; j += 2) {
      int s = __shfl(idx, j + p, 64);
      ushort4 v = *(const ushort4*)(feat + (size_t)s * D + c4);
      a0 += bfu(v.x);
      a1 += bfu(v.y);
      a2 += bfu(v.z);
      a3 += bfu(v.w);
    }
    if (j < cnt) {  // odd tail: only slot 0 contributes
      int s = __shfl(idx, j, 64);
      ushort4 v = *(const ushort4*)(feat + (size_t)s * D + c4);
      float m = (p == 0) ? 1.f : 0.f;
      a0 += m * bfu(v.x);
      a1 += m * bfu(v.y);
      a2 += m * bfu(v.z);
      a3 += m * bfu(v.w);
    }
  }
  a0 += __shfl_xor(a0, 32, 64);
  a1 += __shfl_xor(a1, 32, 64);
  a2 += __shfl_xor(a2, 32, 64);
  a3 += __shfl_xor(a3, 32, 64);
  if (p == 0) {
    float w = inv_deg[node];
    bf16 o[4] = {f2bf(a0 * w), f2bf(a1 * w), f2bf(a2 * w), f2bf(a3 * w)};
    *(ushort4*)(out + (size_t)node * D + c4) = *(const ushort4*)o;
  }
}

// dual gather: aggregate two feature matrices over the same edge walk (same scheme)
__global__ void agg_dual_kernel(const bf16* __restrict__ fAa, const bf16* __restrict__ fAb,
                                const bf16* __restrict__ fBa, const bf16* __restrict__ fBb,
                                const int* __restrict__ flag, const int* __restrict__ esrc,
                                const int* __restrict__ offs, const float* __restrict__ inv_deg,
                                bf16* __restrict__ outA, bf16* __restrict__ outB, int N) {
  int fl = flag[0];
  const bf16* fA = fl ? fAb : fAa;
  const bf16* fB = fl ? fBb : fBa;
  int node = (int)((blockIdx.x * (size_t)blockDim.x + threadIdx.x) >> 6);
  int lane = threadIdx.x & 63;
  if (node >= N) return;
  int e0 = offs[node], e1 = offs[node + 1];
  int p = lane >> 5;
  int c4 = (lane & 31) * 4;
  float a0 = 0.f, a1 = 0.f, a2 = 0.f, a3 = 0.f;
  float b0 = 0.f, b1 = 0.f, b2 = 0.f, b3 = 0.f;
  for (int base = e0; base < e1; base += 64) {
    int cnt = e1 - base;
    if (cnt > 64) cnt = 64;
    int ei = base + lane;
    int idx = esrc[ei < e1 ? ei : (e1 - 1)];
    int j = 0;
    for (; j + 8 <= cnt; j += 8) {
      int s0 = __shfl(idx, j + 0 + p, 64), s1 = __shfl(idx, j + 2 + p, 64);
      int s2 = __shfl(idx, j + 4 + p, 64), s3 = __shfl(idx, j + 6 + p, 64);
      size_t r0 = (size_t)s0 * D + c4, r1 = (size_t)s1 * D + c4;
      size_t r2 = (size_t)s2 * D + c4, r3 = (size_t)s3 * D + c4;
      ushort4 va0 = *(const ushort4*)(fA + r0);
      ushort4 va1 = *(const ushort4*)(fA + r1);
      ushort4 va2 = *(const ushort4*)(fA + r2);
      ushort4 va3 = *(const ushort4*)(fA + r3);
      ushort4 vb0 = *(const ushort4*)(fB + r0);
      ushort4 vb1 = *(const ushort4*)(fB + r1);
      ushort4 vb2 = *(const ushort4*)(fB + r2);
      ushort4 vb3 = *(const ushort4*)(fB + r3);
      a0 += bfu(va0.x) + bfu(va1.x) + bfu(va2.x) + bfu(va3.x);
      a1 += bfu(va0.y) + bfu(va1.y) + bfu(va2.y) + bfu(va3.y);
      a2 += bfu(va0.z) + bfu(va1.z) + bfu(va2.z) + bfu(va3.z);
      a3 += bfu(va0.w) + bfu(va1.w) + bfu(va2.w) + bfu(va3.w);
      b0 += bfu(vb0.x) + bfu(vb1.x) + bfu(vb2.x) + bfu(vb3.x);
      b1 += bfu(vb0.y) + bfu(vb1.y) + bfu(vb2.y) + bfu(vb3.y);
      b2 += bfu(vb0.z) + bfu(vb1.z) + bfu(vb2.z) + bfu(vb3.z);
      b3 += bfu(vb0.w) + bfu(vb1.w) + bfu(vb2.w) + bfu(vb3.w);
    }
    for (; j + 2 <= cnt; j += 2) {
      int s = __shfl(idx, j + p, 64);
      size_t ro = (size_t)s * D + c4;
      ushort4 va = *(const ushort4*)(fA + ro);
      ushort4 vb = *(const ushort4*)(fB + ro);
      a0 += bfu(va.x);
      a1 += bfu(va.y);
      a2 += bfu(va.z);
      a3 += bfu(va.w);
      b0 += bfu(vb.x);
      b1 += bfu(vb.y);
      b2 += bfu(vb.z);
      b3 += bfu(vb.w);
    }
    if (j < cnt) {
      int s = __shfl(idx, j, 64);
      size_t ro = (size_t)s * D + c4;
      ushort4 va = *(const ushort4*)(fA + ro);
      ushort4 vb = *(const ushort4*)(fB + ro);
      float m = (p == 0) ? 1.f : 0.f;
      a0 += m * bfu(va.x);
      a1 += m * bfu(va.y);
      a2 += m * bfu(va.z);
      a3 += m * bfu(va.w);
      b0 += m * bfu(vb.x);
      b1 += m * bfu(vb.y);
      b2 += m * bfu(vb.z);
      b3 += m * bfu(vb.w);
    }
  }
  a0 += __shfl_xor(a0, 32, 64);
  a1 += __shfl_xor(a1, 32, 64);
  a2 += __shfl_xor(a2, 32, 64);
  a3 += __shfl_xor(a3, 32, 64);
  b0 += __shfl_xor(b0, 32, 64);
  b1 += __shfl_xor(b1, 32, 64);
  b2 += __shfl_xor(b2, 32, 64);
  b3 += __shfl_xor(b3, 32, 64);
  if (p == 0) {
    float w = inv_deg[node];
    bf16 oa[4] = {f2bf(a0 * w), f2bf(a1 * w), f2bf(a2 * w), f2bf(a3 * w)};
    bf16 ob[4] = {f2bf(b0 * w), f2bf(b1 * w), f2bf(b2 * w), f2bf(b3 * w)};
    *(ushort4*)(outA + (size_t)node * D + c4) = *(const ushort4*)oa;
    *(ushort4*)(outB + (size_t)node * D + c4) = *(const ushort4*)ob;
  }
}

// ---------------- weight packing: B^T layout [n][k], k = 4 blocks of 128 ----------------

__device__ __forceinline__ float loadw(const void* p, size_t idx, int fl) {
  return fl ? ((const float*)p)[idx] : bf2f(((const bf16*)p)[idx]);
}

__global__ void pack_kernel(const void* __restrict__ Wl, const void* __restrict__ Wr,
                            const void* __restrict__ b, int l, const int* __restrict__ flag,
                            bf16* __restrict__ B1p, bf16* __restrict__ B2p,
                            float* __restrict__ bs1, float* __restrict__ bs2) {
  int fl = flag[0];
  int idx = blockIdx.x * blockDim.x + threadIdx.x;
  const int SZ1 = 256 * 512;
  const int SZ2 = 128 * 512;
  if (idx < SZ1) {
    int n = idx >> 9, k = idx & 511;
    int p = k >> 7, kr = k & 127;
    int gpair = n >> 7, nc = n & 127;
    int gate = gpair * 2 + (p >> 1);
    const void* W = (p & 1) ? Wr : Wl;
    B1p[idx] = f2bf(loadw(W, (((size_t)l * 6 + gate) * D + kr) * D + nc, fl));
  } else if (idx < SZ1 + SZ2) {
    int i2 = idx - SZ1;
    int n = i2 >> 9, k = i2 & 511;
    int p = k >> 7, kr = k & 127;
    int gate = 4 + (p >> 1);
    const void* W = (p & 1) ? Wr : Wl;
    B2p[i2] = f2bf(loadw(W, (((size_t)l * 6 + gate) * D + kr) * D + n, fl));
  } else if (idx < SZ1 + SZ2 + 384) {
    int c = idx - (SZ1 + SZ2);
    if (c < 256) {
      int g0 = (c >> 7) * 2;
      int cc = c & 127;
      bs1[c] = loadw(b, ((size_t)l * 6 + g0) * D + cc, fl) +
               loadw(b, ((size_t)l * 6 + g0 + 1) * D + cc, fl);
    } else {
      int cc = c - 256;
      bs2[cc] = loadw(b, ((size_t)l * 6 + 4) * D + cc, fl) +
                loadw(b, ((size_t)l * 6 + 5) * D + cc, fl);
    }
  }
}

// ---------------- MFMA GEMM mainloop: C[32x128] = A[32x512] @ B[512x128] ----------------
// R8 config (best): BM=32, 40 KB dbuf LDS -> 4 blocks/CU; BN=128 keeps A FETCH at the
// 52 MB ideal. 2-buffer pipeline: next K-tile's global_load_lds issued BEFORE computing
// the current tile; one __syncthreads per step.
// XOR granule swizzle: LDS granule (r, s) holds logical k-granule s^(r&7) of row r.

__device__ __forceinline__ void stage_tile(const bf16* const (&Ablk)[4],
                                           const bf16* __restrict__ Bp, int M, int row0, int col0,
                                           bf16* As, bf16* Bs, int kt, int wave, int r_rel,
                                           int pslot) {
  const bf16* Aptr = Ablk[kt >> 1];
  const int kr = (kt & 1) * 64;
  {  // A: 32 rows, 8 rows per wave-instruction, 1 per wave
    int rchunk = wave * 8;
    int r = rchunk + r_rel;
    int gsrc = pslot ^ (r & 7);
    int rg = row0 + r;
    if (rg > M - 1) rg = M - 1;  // clamp: garbage rows never stored
    const bf16* ga = Aptr + (size_t)rg * D + kr + gsrc * 8;
    bf16* la = As + rchunk * LDSK;  // wave-uniform LDS base
    __builtin_amdgcn_global_load_lds((const GLOBAL_AS unsigned int*)(const void*)ga,
                                     (LDS_AS unsigned int*)(void*)la, 16, 0, 0);
  }
#pragma unroll
  for (int i = 0; i < 4; ++i) {  // B: 128 rows
    int rchunk = wave * 32 + i * 8;
    int r = rchunk + r_rel;
    int gsrc = pslot ^ (r & 7);
    const bf16* gb = Bp + (size_t)(col0 + r) * 512 + kt * 64 + gsrc * 8;
    bf16* lb = Bs + rchunk * LDSK;
    __builtin_amdgcn_global_load_lds((const GLOBAL_AS unsigned int*)(const void*)gb,
                                     (LDS_AS unsigned int*)(void*)lb, 16, 0, 0);
  }
}

__device__ __forceinline__ void gemm_mainloop(const bf16* A0, const bf16* A1, const bf16* A2,
                                              const bf16* A3, const bf16* __restrict__ Bp, int M,
                                              int row0, int col0, bf16* As, bf16* Bs,
                                              f32x4 (&acc)[1][4]) {
  int tid = threadIdx.x;
  int wave = tid >> 6, lane = tid & 63;
  int wrow = (wave >> 1) * 16, wcol = (wave & 1) * 64;
  const bf16* Ablk[4] = {A0, A1, A2, A3};
  int r_rel = lane >> 3;  // 0..7 within the 8-row chunk
  int pslot = lane & 7;   // physical granule this lane writes
  int quad = lane >> 4, mr = lane & 15;
  const int ABUF = BM * LDSK;  // 2048 elems per buffer
  const int BBUF = BN * LDSK;  // 8192 elems per buffer

  // prologue: stage tile 0 into buffer 0
  stage_tile(Ablk, Bp, M, row0, col0, As, Bs, 0, wave, r_rel, pslot);
  __syncthreads();

#pragma unroll
  for (int kt = 0; kt < 8; ++kt) {
    const int cur = kt & 1;
    // prefetch next K-tile into the other buffer (overlaps with compute below)
    if (kt < 7)
      stage_tile(Ablk, Bp, M, row0, col0, As + (cur ^ 1) * ABUF, Bs + (cur ^ 1) * BBUF, kt + 1,
                 wave, r_rel, pslot);
    const bf16* Asc = As + cur * ABUF;
    const bf16* Bsc = Bs + cur * BBUF;
#pragma unroll
    for (int kk = 0; kk < 2; ++kk) {
      int G = kk * 4 + quad;  // logical granule for this lane's fragment
      bf16x8 af, bfv[4];
      {
        int R = wrow + mr;
        af = *(const bf16x8*)(const void*)(Asc + R * LDSK + ((G ^ (R & 7)) * 8));
      }
#pragma unroll
      for (int ni = 0; ni < 4; ++ni) {
        int R = wcol + ni * 16 + mr;
        bfv[ni] = *(const bf16x8*)(const void*)(Bsc + R * LDSK + ((G ^ (R & 7)) * 8));
      }
#pragma unroll
      for (int ni = 0; ni < 4; ++ni)
        acc[0][ni] =
            __builtin_amdgcn_mfma_f32_16x16x32_bf16(af, bfv[ni], acc[0][ni], 0, 0, 0);
    }
    // one barrier per step: waits prefetch (implicit vmcnt(0)) + protects buffer reuse
    __syncthreads();
  }
}

// GEMM1: cols 0..127 -> z = sigmoid(.) (fp16); cols 128..255 -> rh = sigmoid(.)*h (bf16)
__global__ __launch_bounds__(256) void gemm1_kernel(
    const bf16* A0, const bf16* A1a, const bf16* A1b, const bf16* A2, const bf16* A3a,
    const bf16* A3b, const int* __restrict__ flag, const bf16* __restrict__ Bp,
    const float* __restrict__ bias, __half* __restrict__ z, bf16* __restrict__ rh, int M) {
  int fl = flag[0];
  const bf16* A1 = fl ? A1b : A1a;
  const bf16* A3 = fl ? A3b : A3a;
  const bf16* hl = A3;
  __shared__ bf16 As[2 * BM * LDSK];
  __shared__ bf16 Bs[2 * BN * LDSK];
  f32x4 acc[1][4];
#pragma unroll
  for (int j = 0; j < 4; ++j) acc[0][j] = (f32x4){0.f, 0.f, 0.f, 0.f};
  int row0 = blockIdx.x * BM, col0 = blockIdx.y * BN;  // row-fastest grid: FETCH-friendly (R0)
  gemm_mainloop(A0, A1, A2, A3, Bp, M, row0, col0, As, Bs, acc);
  int lane = threadIdx.x & 63, wave = threadIdx.x >> 6;
  int wrow = (wave >> 1) * 16, wcol = (wave & 1) * 64;
  int mr = lane & 15, quad = lane >> 4;
#pragma unroll
  for (int ni = 0; ni < 4; ++ni)
#pragma unroll
    for (int r = 0; r < 4; ++r) {
      int grow = row0 + wrow + quad * 4 + r;
      if (grow >= M) continue;
      int gcol = col0 + wcol + ni * 16 + mr;
      float v = acc[0][ni][r] + bias[gcol];
      float sg = 1.0f / (1.0f + __expf(-v));
      if (gcol < 128) {
        z[(size_t)grow * D + gcol] = __float2half(sg);
      } else {
        int cc = gcol - 128;
        float hv = bf2f(hl[(size_t)grow * D + cc]);
        rh[(size_t)grow * D + cc] = f2bf(sg * hv);
      }
    }
}

// GEMM2: out = z*h + (1-z)*tanh(pre); out dtype per flag; bf16 shadow into nextb (fp32 mode)
__global__ __launch_bounds__(256) void gemm2_kernel(
    const bf16* A0, const bf16* A1a, const bf16* A1b, const bf16* A2, const bf16* A3,
    const bf16* A3hA, const bf16* A3hB, const int* __restrict__ flag, const bf16* __restrict__ Bp,
    const float* __restrict__ bias, const __half* __restrict__ z, void* __restrict__ outbase,
    size_t lND, bf16* __restrict__ nextb, int M) {
  int fl = flag[0];
  const bf16* A1 = fl ? A1b : A1a;
  const bf16* hl = fl ? A3hB : A3hA;
  __shared__ bf16 As[2 * BM * LDSK];
  __shared__ bf16 Bs[2 * BN * LDSK];
  f32x4 acc[1][4];
#pragma unroll
  for (int j = 0; j < 4; ++j) acc[0][j] = (f32x4){0.f, 0.f, 0.f, 0.f};
  int row0 = blockIdx.x * BM, col0 = 0;
  gemm_mainloop(A0, A1, A2, A3, Bp, M, row0, col0, As, Bs, acc);
  int lane = threadIdx.x & 63, wave = threadIdx.x >> 6;
  int wrow = (wave >> 1) * 16, wcol = (wave & 1) * 64;
  int mr = lane & 15, quad = lane >> 4;
#pragma unroll
  for (int ni = 0; ni < 4; ++ni)
#pragma unroll
    for (int r = 0; r < 4; ++r) {
      int grow = row0 + wrow + quad * 4 + r;
      if (grow >= M) continue;
      int gcol = col0 + wcol + ni * 16 + mr;
      float pre = acc[0][ni][r] + bias[gcol];
      float ht = tanhf(pre);
      size_t off = (size_t)grow * D + gcol;
      float zv = __half2float(z[off]);
      float hv = bf2f(hl[off]);
      float ov = zv * hv + (1.0f - zv) * ht;
      if (fl) {
        ((float*)outbase)[lND + off] = ov;
        nextb[off] = f2bf(ov);
      } else {
        ((bf16*)outbase)[lND + off] = f2bf(ov);
      }
    }
}

// ---------------- launch ----------------

extern "C" void kernel_launch(void* const* d_in, const int* in_sizes, int n_in, void* d_out,
                              int out_size, void* d_ws, size_t ws_size, hipStream_t stream) {
  const void* x = d_in[0];
  const void* h = d_in[1];
  const void* Wl = d_in[2];
  const void* Wr = d_in[3];
  const void* b = d_in[4];
  const int* src = (const int*)d_in[5];
  const int* dst = (const int*)d_in[6];

  const int NX = in_sizes[0];
  const int NH = in_sizes[1];
  const int N = NX / D;
  const int E = in_sizes[5];
  const int L = NH / NX;
  (void)n_in;
  (void)out_size;
  (void)ws_size;

  char* ws = (char*)d_ws;
  size_t off = 0;
  auto alloc = [&](size_t bytes) -> char* {
    char* p = ws + off;
    off = (off + bytes + 255) & ~(size_t)255;
    return p;
  };
  int* flag = (int*)alloc(256);
  int* deg = (int*)alloc((size_t)N * 4);
  int* offs = (int*)alloc((size_t)(N + 1) * 4);
  int* cursor = (int*)alloc((size_t)N * 4);
  float* inv_deg = (float*)alloc((size_t)N * 4);
  int* bsum = (int*)alloc(256 * 4);
  int* esrc = (int*)alloc((size_t)E * 4);
  bf16* agg_inp = (bf16*)alloc((size_t)N * D * 2);
  bf16* agg2 = (bf16*)alloc((size_t)N * D * 2);
  bf16* rh = (bf16*)alloc((size_t)N * D * 2);
  __half* z = (__half*)alloc((size_t)N * D * 2);
  bf16* B1p = (bf16*)alloc(256 * 512 * 2);
  bf16* B2p = (bf16*)alloc(128 * 512 * 2);
  float* bs1 = (float*)alloc(256 * 4);
  float* bs2 = (float*)alloc(128 * 4);
  bf16* xb = (bf16*)alloc((size_t)NX * 2);  // fp32 mode only
  bf16* hb = (bf16*)alloc((size_t)NH * 2);  // fp32 mode only

  probe_kernel<<<1, 256, 0, stream>>>((const unsigned short*)Wl, in_sizes[2], flag);
  int ncv = NX > NH ? NX : NH;
  convert_kernel<<<(ncv / 4 + 255) / 256, 256, 0, stream>>>((const float*)x, (const float*)h, xb,
                                                            hb, flag, NX, NH);

  zero_int_kernel<<<(N + 255) / 256, 256, 0, stream>>>(deg, N);
  count_deg_kernel<<<(E + 255) / 256, 256, 0, stream>>>(dst, deg, E);
  int nb = (N + SCAN_BLK - 1) / SCAN_BLK;  // 49 for N=50000; scan2 handles nb<=256
  scan1_kernel<<<nb, 256, 0, stream>>>(deg, bsum, N);
  scan2_kernel<<<1, 256, 0, stream>>>(bsum, nb);
  scan3_kernel<<<nb, 256, 0, stream>>>(deg, bsum, offs, cursor, inv_deg, N, E);
  scatter_kernel<<<(E + 255) / 256, 256, 0, stream>>>(src, dst, cursor, esrc, E);

  int mtiles = (N + BM - 1) / BM;
  const int pack_elems = 256 * 512 + 128 * 512 + 384;
  for (int l = 0; l < L; ++l) {
    const size_t lND = (size_t)l * N * D;
    const bf16* inpA = (l == 0) ? (const bf16*)x : ((const bf16*)d_out + lND - (size_t)N * D);
    const bf16* hlA = (const bf16*)h + lND;
    const bf16* hlB = hb + lND;

    pack_kernel<<<(pack_elems + 255) / 256, 256, 0, stream>>>(Wl, Wr, b, l, flag, B1p, B2p, bs1,
                                                              bs2);
    agg_dual_kernel<<<(N + 3) / 4, 256, 0, stream>>>(inpA, xb, hlA, hlB, flag, esrc, offs, inv_deg,
                                                     agg_inp, agg2, N);
    gemm1_kernel<<<dim3(mtiles, 2), 256, 0, stream>>>(agg_inp, inpA, xb, agg2, hlA, hlB, flag, B1p,
                                                      bs1, z, rh, N);
    agg_kernel<<<(N + 3) / 4, 256, 0, stream>>>(rh, rh, flag, esrc, offs, inv_deg, agg2, N);
    gemm2_kernel<<<dim3(mtiles, 1), 256, 0, stream>>>(agg_inp, inpA, xb, agg2, rh, hlA, hlB, flag,
                                                      B2p, bs2, z, d_out, lND, xb, N);
  }
}

// Round 11
// 579.768 us; speedup vs baseline: 1.1610x; 1.0113x over previous
//
#include <hip/hip_runtime.h>
#include <hip/hip_bf16.h>
#include <hip/hip_fp16.h>

#define D 128
#define BM 32
#define BN 128
#define LDSK 64  // unpadded k-stride; bank conflicts handled by XOR granule swizzle
#define SCAN_BLK 1024  // elements per scan block (256 thr x 4)

#define GLOBAL_AS __attribute__((address_space(1)))
#define LDS_AS __attribute__((address_space(3)))

typedef __attribute__((ext_vector_type(8))) __bf16 bf16x8;
typedef __attribute__((ext_vector_type(4))) float f32x4;
typedef __attribute__((ext_vector_type(8))) unsigned short ushort8;
typedef __hip_bfloat16 bf16;

__device__ __forceinline__ float bf2f(bf16 v) { return __bfloat162float(v); }
__device__ __forceinline__ bf16 f2bf(float v) { return __float2bfloat16(v); }
__device__ __forceinline__ float bfu(unsigned short u) {
  return __uint_as_float(((unsigned int)u) << 16);
}

// ---------------- dtype probe: are the float tensors bf16 or fp32? ----------------
// Vectorized: uint4 (16B) independent loads per thread, 8192 words total.
__global__ void probe_kernel(const unsigned short* __restrict__ w, int n, int* __restrict__ flag) {
  __shared__ int cnt[256];
  int t = threadIdx.x;
  int bad = 0;
  int lim4 = n / 8 < 1024 ? n / 8 : 1024;  // number of uint4 groups (8 words each)
  const uint4* w4 = (const uint4*)w;
  for (int i = t; i < lim4; i += 256) {
    uint4 v = w4[i];
    unsigned int ws[8] = {v.x & 0xffffu, v.x >> 16, v.y & 0xffffu, v.y >> 16,
                          v.z & 0xffffu, v.z >> 16, v.w & 0xffffu, v.w >> 16};
#pragma unroll
    for (int j = 0; j < 8; ++j) {
      float f = __uint_as_float(ws[j] << 16);
      if (!(fabsf(f) <= 4.0f)) bad++;  // catches NaN too
    }
  }
  cnt[t] = bad;
  __syncthreads();
  for (int off = 128; off > 0; off >>= 1) {
    if (t < off) cnt[t] += cnt[t + off];
    __syncthreads();
  }
  if (t == 0) flag[0] = (cnt[0] > 512) ? 1 : 0;
}

// fp32 mode only: materialize canonical bf16 copies of x and h. Vectorized x4.
__global__ void convert_kernel(const float* __restrict__ xf, const float* __restrict__ hf,
                               bf16* __restrict__ xb, bf16* __restrict__ hb,
                               const int* __restrict__ flag, int nx, int nh) {
  if (flag[0] == 0) return;
  int i = (blockIdx.x * blockDim.x + threadIdx.x) * 4;
  if (i + 3 < nx) {
    float4 v = *(const float4*)(xf + i);
    bf16 o[4] = {f2bf(v.x), f2bf(v.y), f2bf(v.z), f2bf(v.w)};
    *(ushort4*)(xb + i) = *(const ushort4*)o;
  } else {
    for (int j = 0; j < 4; ++j)
      if (i + j < nx) xb[i + j] = f2bf(xf[i + j]);
  }
  if (i + 3 < nh) {
    float4 v = *(const float4*)(hf + i);
    bf16 o[4] = {f2bf(v.x), f2bf(v.y), f2bf(v.z), f2bf(v.w)};
    *(ushort4*)(hb + i) = *(const ushort4*)o;
  } else {
    for (int j = 0; j < 4; ++j)
      if (i + j < nh) hb[i + j] = f2bf(hf[i + j]);
  }
}

// ---------------- graph preprocessing ----------------

__global__ void zero_int_kernel(int* p, int n) {
  int i = blockIdx.x * blockDim.x + threadIdx.x;
  if (i < n) p[i] = 0;
}

__global__ void count_deg_kernel(const int* __restrict__ dst, int* __restrict__ deg, int E) {
  int e = blockIdx.x * blockDim.x + threadIdx.x;
  if (e < E) atomicAdd(&deg[dst[e]], 1);
}

// phase 1: per-block sums of 1024 deg values
__global__ void scan1_kernel(const int* __restrict__ deg, int* __restrict__ bsum, int N) {
  __shared__ int lsum[256];
  int t = threadIdx.x;
  int base = blockIdx.x * SCAN_BLK + t * 4;
  int s = 0;
  if (base + 3 < N) {
    int4 v = *(const int4*)(deg + base);
    s = v.x + v.y + v.z + v.w;
  } else {
    for (int i = 0; i < 4; ++i)
      if (base + i < N) s += deg[base + i];
  }
  lsum[t] = s;
  __syncthreads();
  for (int off = 128; off > 0; off >>= 1) {
    if (t < off) lsum[t] += lsum[t + off];
    __syncthreads();
  }
  if (t == 0) bsum[blockIdx.x] = lsum[0];
}

// phase 2: exclusive scan of block sums (nb <= 256), single block
__global__ void scan2_kernel(int* __restrict__ bsum, int nb) {
  __shared__ int sh[256];
  int t = threadIdx.x;
  sh[t] = (t < nb) ? bsum[t] : 0;
  __syncthreads();
  for (int off = 1; off < 256; off <<= 1) {
    int v = sh[t];
    int add = (t >= off) ? sh[t - off] : 0;
    __syncthreads();
    sh[t] = v + add;
    __syncthreads();
  }
  if (t < nb) bsum[t] = (t == 0) ? 0 : sh[t - 1];
}

// phase 3: per-block local scan + block offset -> offs/cursor/inv_deg
__global__ void scan3_kernel(const int* __restrict__ deg, const int* __restrict__ bsum,
                             int* __restrict__ offs, int* __restrict__ cursor,
                             float* __restrict__ inv_deg, int N, int E) {
  __shared__ int lsum[256];
  int t = threadIdx.x;
  int base = blockIdx.x * SCAN_BLK + t * 4;
  int d0 = 0, d1 = 0, d2 = 0, d3 = 0;
  if (base + 3 < N) {
    int4 v = *(const int4*)(deg + base);
    d0 = v.x; d1 = v.y; d2 = v.z; d3 = v.w;
  } else {
    if (base + 0 < N) d0 = deg[base + 0];
    if (base + 1 < N) d1 = deg[base + 1];
    if (base + 2 < N) d2 = deg[base + 2];
    if (base + 3 < N) d3 = deg[base + 3];
  }
  lsum[t] = d0 + d1 + d2 + d3;
  __syncthreads();
  for (int off = 1; off < 256; off <<= 1) {
    int v = lsum[t];
    int add = (t >= off) ? lsum[t - off] : 0;
    __syncthreads();
    lsum[t] = v + add;
    __syncthreads();
  }
  int run = bsum[blockIdx.x] + ((t == 0) ? 0 : lsum[t - 1]);
  int dd[4] = {d0, d1, d2, d3};
  for (int i = 0; i < 4; ++i) {
    int idx = base + i;
    if (idx < N) {
      offs[idx] = run;
      cursor[idx] = run;
      inv_deg[idx] = 1.0f / (float)(dd[i] > 1 ? dd[i] : 1);
      run += dd[i];
    }
  }
  if (blockIdx.x == 0 && t == 0) offs[N] = E;
}

__global__ void scatter_kernel(const int* __restrict__ src, const int* __restrict__ dst,
                               int* __restrict__ cursor, int* __restrict__ esrc, int E) {
  int e = blockIdx.x * blockDim.x + threadIdx.x;
  if (e < E) {
    int pos = atomicAdd(&cursor[dst[e]], 1);
    esrc[pos] = src[e];
  }
}

// ---------------- mean aggregation (CSR gather, one wave per node) ----------------
// 16B/lane gather: lanes split into FOUR row-slots (p = lane>>4); each vector-memory
// instruction gathers FOUR rows (16 lanes x ushort8 each) -> quarter the gather
// instructions / shfl broadcasts of the 4B version. Two-stage __shfl_xor(16,32)
// cross-slot reduce at the end; lanes 0..15 write ushort8 (256B coalesced row).

__global__ void agg_kernel(const bf16* __restrict__ featA, const bf16* __restrict__ featB,
                           const int* __restrict__ flag, const int* __restrict__ esrc,
                           const int* __restrict__ offs, const float* __restrict__ inv_deg,
                           bf16* __restrict__ out, int N) {
  const bf16* feat = flag[0] ? featB : featA;
  int node = (int)((blockIdx.x * (size_t)blockDim.x + threadIdx.x) >> 6);
  int lane = threadIdx.x & 63;
  if (node >= N) return;
  int e0 = offs[node], e1 = offs[node + 1];
  int p = lane >> 4;         // row slot within a 4-edge group
  int c8 = (lane & 15) * 8;  // 8 cols per lane
  float a[8] = {0.f, 0.f, 0.f, 0.f, 0.f, 0.f, 0.f, 0.f};
  for (int base = e0; base < e1; base += 64) {
    int cnt = e1 - base;
    if (cnt > 64) cnt = 64;
    int ei = base + lane;
    int idx = esrc[ei < e1 ? ei : (e1 - 1)];
    int j = 0;
    for (; j + 8 <= cnt; j += 8) {
      int s0 = __shfl(idx, j + p, 64);
      int s1 = __shfl(idx, j + 4 + p, 64);
      ushort8 v0 = *(const ushort8*)(feat + (size_t)s0 * D + c8);
      ushort8 v1 = *(const ushort8*)(feat + (size_t)s1 * D + c8);
#pragma unroll
      for (int q = 0; q < 8; ++q) a[q] += bfu(v0[q]) + bfu(v1[q]);
    }
    for (; j + 4 <= cnt; j += 4) {
      int s = __shfl(idx, j + p, 64);
      ushort8 v = *(const ushort8*)(feat + (size_t)s * D + c8);
#pragma unroll
      for (int q = 0; q < 8; ++q) a[q] += bfu(v[q]);
    }
    if (j < cnt) {  // partial group: mask out slots past the end
      int jp = j + p;
      int s = __shfl(idx, jp < cnt ? jp : cnt - 1, 64);
      ushort8 v = *(const ushort8*)(feat + (size_t)s * D + c8);
      float m = (jp < cnt) ? 1.f : 0.f;
#pragma unroll
      for (int q = 0; q < 8; ++q) a[q] += m * bfu(v[q]);
    }
  }
#pragma unroll
  for (int q = 0; q < 8; ++q) {
    a[q] += __shfl_xor(a[q], 16, 64);
    a[q] += __shfl_xor(a[q], 32, 64);
  }
  if (lane < 16) {
    float w = inv_deg[node];
    bf16 o[8];
#pragma unroll
    for (int q = 0; q < 8; ++q) o[q] = f2bf(a[q] * w);
    *(ushort8*)(out + (size_t)node * D + c8) = *(const ushort8*)o;
  }
}

// dual gather: aggregate two feature matrices over the same edge walk (same scheme)
__global__ void agg_dual_kernel(const bf16* __restrict__ fAa, const bf16* __restrict__ fAb,
                                const bf16* __restrict__ fBa, const bf16* __restrict__ fBb,
                                const int* __restrict__ flag, const int* __restrict__ esrc,
                                const int* __restrict__ offs, const float* __restrict__ inv_deg,
                                bf16* __restrict__ outA, bf16* __restrict__ outB, int N) {
  int fl = flag[0];
  const bf16* fA = fl ? fAb : fAa;
  const bf16* fB = fl ? fBb : fBa;
  int node = (int)((blockIdx.x * (size_t)blockDim.x + threadIdx.x) >> 6);
  int lane = threadIdx.x & 63;
  if (node >= N) return;
  int e0 = offs[node], e1 = offs[node + 1];
  int p = lane >> 4;
  int c8 = (lane & 15) * 8;
  float a[8] = {0.f, 0.f, 0.f, 0.f, 0.f, 0.f, 0.f, 0.f};
  float b[8] = {0.f, 0.f, 0.f, 0.f, 0.f, 0.f, 0.f, 0.f};
  for (int base = e0; base < e1; base += 64) {
    int cnt = e1 - base;
    if (cnt > 64) cnt = 64;
    int ei = base + lane;
    int idx = esrc[ei < e1 ? ei : (e1 - 1)];
    int j = 0;
    for (; j + 8 <= cnt; j += 8) {
      int s0 = __shfl(idx, j + p, 64);
      int s1 = __shfl(idx, j + 4 + p, 64);
      size_t r0 = (size_t)s0 * D + c8, r1 = (size_t)s1 * D + c8;
      ushort8 va0 = *(const ushort8*)(fA + r0);
      ushort8 va1 = *(const ushort8*)(fA + r1);
      ushort8 vb0 = *(const ushort8*)(fB + r0);
      ushort8 vb1 = *(const ushort8*)(fB + r1);
#pragma unroll
      for (int q = 0; q < 8; ++q) {
        a[q] += bfu(va0[q]) + bfu(va1[q]);
        b[q] += bfu(vb0[q]) + bfu(vb1[q]);
      }
    }
    for (; j + 4 <= cnt; j += 4) {
      int s = __shfl(idx, j + p, 64);
      size_t ro = (size_t)s * D + c8;
      ushort8 va = *(const ushort8*)(fA + ro);
      ushort8 vb = *(const ushort8*)(fB + ro);
#pragma unroll
      for (int q = 0; q < 8; ++q) {
        a[q] += bfu(va[q]);
        b[q] += bfu(vb[q]);
      }
    }
    if (j < cnt) {
      int jp = j + p;
      int s = __shfl(idx, jp < cnt ? jp : cnt - 1, 64);
      size_t ro = (size_t)s * D + c8;
      ushort8 va = *(const ushort8*)(fA + ro);
      ushort8 vb = *(const ushort8*)(fB + ro);
      float m = (jp < cnt) ? 1.f : 0.f;
#pragma unroll
      for (int q = 0; q < 8; ++q) {
        a[q] += m * bfu(va[q]);
        b[q] += m * bfu(vb[q]);
      }
    }
  }
#pragma unroll
  for (int q = 0; q < 8; ++q) {
    a[q] += __shfl_xor(a[q], 16, 64);
    a[q] += __shfl_xor(a[q], 32, 64);
    b[q] += __shfl_xor(b[q], 16, 64);
    b[q] += __shfl_xor(b[q], 32, 64);
  }
  if (lane < 16) {
    float w = inv_deg[node];
    bf16 oa[8], ob[8];
#pragma unroll
    for (int q = 0; q < 8; ++q) {
      oa[q] = f2bf(a[q] * w);
      ob[q] = f2bf(b[q] * w);
    }
    *(ushort8*)(outA + (size_t)node * D + c8) = *(const ushort8*)oa;
    *(ushort8*)(outB + (size_t)node * D + c8) = *(const ushort8*)ob;
  }
}

// ---------------- weight packing: B^T layout [n][k], k = 4 blocks of 128 ----------------
// Single launch packs ALL layers (weight-only; no per-layer dependency).

__device__ __forceinline__ float loadw(const void* p, size_t idx, int fl) {
  return fl ? ((const float*)p)[idx] : bf2f(((const bf16*)p)[idx]);
}

#define PACK_SZ1 (256 * 512)
#define PACK_SZ2 (128 * 512)
#define PACK_P (PACK_SZ1 + PACK_SZ2 + 384)

__global__ void pack_kernel(const void* __restrict__ Wl, const void* __restrict__ Wr,
                            const void* __restrict__ b, int L, const int* __restrict__ flag,
                            bf16* __restrict__ B1p, bf16* __restrict__ B2p,
                            float* __restrict__ bs1, float* __restrict__ bs2) {
  int fl = flag[0];
  int gidx = blockIdx.x * blockDim.x + threadIdx.x;
  int l = gidx / PACK_P;
  if (l >= L) return;
  int idx = gidx - l * PACK_P;
  bf16* B1 = B1p + (size_t)l * PACK_SZ1;
  bf16* B2 = B2p + (size_t)l * PACK_SZ2;
  float* b1 = bs1 + (size_t)l * 256;
  float* b2 = bs2 + (size_t)l * 128;
  if (idx < PACK_SZ1) {
    int n = idx >> 9, k = idx & 511;
    int p = k >> 7, kr = k & 127;
    int gpair = n >> 7, nc = n & 127;
    int gate = gpair * 2 + (p >> 1);
    const void* W = (p & 1) ? Wr : Wl;
    B1[idx] = f2bf(loadw(W, (((size_t)l * 6 + gate) * D + kr) * D + nc, fl));
  } else if (idx < PACK_SZ1 + PACK_SZ2) {
    int i2 = idx - PACK_SZ1;
    int n = i2 >> 9, k = i2 & 511;
    int p = k >> 7, kr = k & 127;
    int gate = 4 + (p >> 1);
    const void* W = (p & 1) ? Wr : Wl;
    B2[i2] = f2bf(loadw(W, (((size_t)l * 6 + gate) * D + kr) * D + n, fl));
  } else {
    int c = idx - (PACK_SZ1 + PACK_SZ2);
    if (c < 256) {
      int g0 = (c >> 7) * 2;
      int cc = c & 127;
      b1[c] = loadw(b, ((size_t)l * 6 + g0) * D + cc, fl) +
              loadw(b, ((size_t)l * 6 + g0 + 1) * D + cc, fl);
    } else {
      int cc = c - 256;
      b2[cc] = loadw(b, ((size_t)l * 6 + 4) * D + cc, fl) +
               loadw(b, ((size_t)l * 6 + 5) * D + cc, fl);
    }
  }
}

// ---------------- MFMA GEMM mainloop: C[32x128] = A[32x512] @ B[512x128] ----------------
// R8 config (best): BM=32, 40 KB dbuf LDS -> 4 blocks/CU; BN=128 keeps A FETCH at the
// 52 MB ideal. 2-buffer pipeline: next K-tile's global_load_lds issued BEFORE computing
// the current tile; one __syncthreads per step.
// XOR granule swizzle: LDS granule (r, s) holds logical k-granule s^(r&7) of row r.

__device__ __forceinline__ void stage_tile(const bf16* const (&Ablk)[4],
                                           const bf16* __restrict__ Bp, int M, int row0, int col0,
                                           bf16* As, bf16* Bs, int kt, int wave, int r_rel,
                                           int pslot) {
  const bf16* Aptr = Ablk[kt >> 1];
  const int kr = (kt & 1) * 64;
  {  // A: 32 rows, 8 rows per wave-instruction, 1 per wave
    int rchunk = wave * 8;
    int r = rchunk + r_rel;
    int gsrc = pslot ^ (r & 7);
    int rg = row0 + r;
    if (rg > M - 1) rg = M - 1;  // clamp: garbage rows never stored
    const bf16* ga = Aptr + (size_t)rg * D + kr + gsrc * 8;
    bf16* la = As + rchunk * LDSK;  // wave-uniform LDS base
    __builtin_amdgcn_global_load_lds((const GLOBAL_AS unsigned int*)(const void*)ga,
                                     (LDS_AS unsigned int*)(void*)la, 16, 0, 0);
  }
#pragma unroll
  for (int i = 0; i < 4; ++i) {  // B: 128 rows
    int rchunk = wave * 32 + i * 8;
    int r = rchunk + r_rel;
    int gsrc = pslot ^ (r & 7);
    const bf16* gb = Bp + (size_t)(col0 + r) * 512 + kt * 64 + gsrc * 8;
    bf16* lb = Bs + rchunk * LDSK;
    __builtin_amdgcn_global_load_lds((const GLOBAL_AS unsigned int*)(const void*)gb,
                                     (LDS_AS unsigned int*)(void*)lb, 16, 0, 0);
  }
}

__device__ __forceinline__ void gemm_mainloop(const bf16* A0, const bf16* A1, const bf16* A2,
                                              const bf16* A3, const bf16* __restrict__ Bp, int M,
                                              int row0, int col0, bf16* As, bf16* Bs,
                                              f32x4 (&acc)[1][4]) {
  int tid = threadIdx.x;
  int wave = tid >> 6, lane = tid & 63;
  int wrow = (wave >> 1) * 16, wcol = (wave & 1) * 64;
  const bf16* Ablk[4] = {A0, A1, A2, A3};
  int r_rel = lane >> 3;  // 0..7 within the 8-row chunk
  int pslot = lane & 7;   // physical granule this lane writes
  int quad = lane >> 4, mr = lane & 15;
  const int ABUF = BM * LDSK;  // 2048 elems per buffer
  const int BBUF = BN * LDSK;  // 8192 elems per buffer

  // prologue: stage tile 0 into buffer 0
  stage_tile(Ablk, Bp, M, row0, col0, As, Bs, 0, wave, r_rel, pslot);
  __syncthreads();

#pragma unroll
  for (int kt = 0; kt < 8; ++kt) {
    const int cur = kt & 1;
    // prefetch next K-tile into the other buffer (overlaps with compute below)
    if (kt < 7)
      stage_tile(Ablk, Bp, M, row0, col0, As + (cur ^ 1) * ABUF, Bs + (cur ^ 1) * BBUF, kt + 1,
                 wave, r_rel, pslot);
    const bf16* Asc = As + cur * ABUF;
    const bf16* Bsc = Bs + cur * BBUF;
#pragma unroll
    for (int kk = 0; kk < 2; ++kk) {
      int G = kk * 4 + quad;  // logical granule for this lane's fragment
      bf16x8 af, bfv[4];
      {
        int R = wrow + mr;
        af = *(const bf16x8*)(const void*)(Asc + R * LDSK + ((G ^ (R & 7)) * 8));
      }
#pragma unroll
      for (int ni = 0; ni < 4; ++ni) {
        int R = wcol + ni * 16 + mr;
        bfv[ni] = *(const bf16x8*)(const void*)(Bsc + R * LDSK + ((G ^ (R & 7)) * 8));
      }
#pragma unroll
      for (int ni = 0; ni < 4; ++ni)
        acc[0][ni] =
            __builtin_amdgcn_mfma_f32_16x16x32_bf16(af, bfv[ni], acc[0][ni], 0, 0, 0);
    }
    // one barrier per step: waits prefetch (implicit vmcnt(0)) + protects buffer reuse
    __syncthreads();
  }
}

// GEMM1: cols 0..127 -> z = sigmoid(.) (fp16); cols 128..255 -> rh = sigmoid(.)*h (bf16)
__global__ __launch_bounds__(256) void gemm1_kernel(
    const bf16* A0, const bf16* A1a, const bf16* A1b, const bf16* A2, const bf16* A3a,
    const bf16* A3b, const int* __restrict__ flag, const bf16* __restrict__ Bp,
    const float* __restrict__ bias, __half* __restrict__ z, bf16* __restrict__ rh, int M) {
  int fl = flag[0];
  const bf16* A1 = fl ? A1b : A1a;
  const bf16* A3 = fl ? A3b : A3a;
  const bf16* hl = A3;
  __shared__ bf16 As[2 * BM * LDSK];
  __shared__ bf16 Bs[2 * BN * LDSK];
  f32x4 acc[1][4];
#pragma unroll
  for (int j = 0; j < 4; ++j) acc[0][j] = (f32x4){0.f, 0.f, 0.f, 0.f};
  int row0 = blockIdx.x * BM, col0 = blockIdx.y * BN;  // row-fastest grid: FETCH-friendly (R0)
  gemm_mainloop(A0, A1, A2, A3, Bp, M, row0, col0, As, Bs, acc);
  int lane = threadIdx.x & 63, wave = threadIdx.x >> 6;
  int wrow = (wave >> 1) * 16, wcol = (wave & 1) * 64;
  int mr = lane & 15, quad = lane >> 4;
#pragma unroll
  for (int ni = 0; ni < 4; ++ni)
#pragma unroll
    for (int r = 0; r < 4; ++r) {
      int grow = row0 + wrow + quad * 4 + r;
      if (grow >= M) continue;
      int gcol = col0 + wcol + ni * 16 + mr;
      float v = acc[0][ni][r] + bias[gcol];
      float sg = 1.0f / (1.0f + __expf(-v));
      if (gcol < 128) {
        z[(size_t)grow * D + gcol] = __float2half(sg);
      } else {
        int cc = gcol - 128;
        float hv = bf2f(hl[(size_t)grow * D + cc]);
        rh[(size_t)grow * D + cc] = f2bf(sg * hv);
      }
    }
}

// GEMM2: out = z*h + (1-z)*tanh(pre); out dtype per flag; bf16 shadow into nextb
// (fp32 mode, non-last layer only — nextb==nullptr skips the dead write)
__global__ __launch_bounds__(256) void gemm2_kernel(
    const bf16* A0, const bf16* A1a, const bf16* A1b, const bf16* A2, const bf16* A3,
    const bf16* A3hA, const bf16* A3hB, const int* __restrict__ flag, const bf16* __restrict__ Bp,
    const float* __restrict__ bias, const __half* __restrict__ z, void* __restrict__ outbase,
    size_t lND, bf16* __restrict__ nextb, int M) {
  int fl = flag[0];
  const bf16* A1 = fl ? A1b : A1a;
  const bf16* hl = fl ? A3hB : A3hA;
  __shared__ bf16 As[2 * BM * LDSK];
  __shared__ bf16 Bs[2 * BN * LDSK];
  f32x4 acc[1][4];
#pragma unroll
  for (int j = 0; j < 4; ++j) acc[0][j] = (f32x4){0.f, 0.f, 0.f, 0.f};
  int row0 = blockIdx.x * BM, col0 = 0;
  gemm_mainloop(A0, A1, A2, A3, Bp, M, row0, col0, As, Bs, acc);
  int lane = threadIdx.x & 63, wave = threadIdx.x >> 6;
  int wrow = (wave >> 1) * 16, wcol = (wave & 1) * 64;
  int mr = lane & 15, quad = lane >> 4;
#pragma unroll
  for (int ni = 0; ni < 4; ++ni)
#pragma unroll
    for (int r = 0; r < 4; ++r) {
      int grow = row0 + wrow + quad * 4 + r;
      if (grow >= M) continue;
      int gcol = col0 + wcol + ni * 16 + mr;
      float pre = acc[0][ni][r] + bias[gcol];
      float ht = tanhf(pre);
      size_t off = (size_t)grow * D + gcol;
      float zv = __half2float(z[off]);
      float hv = bf2f(hl[off]);
      float ov = zv * hv + (1.0f - zv) * ht;
      if (fl) {
        ((float*)outbase)[lND + off] = ov;
        if (nextb) nextb[off] = f2bf(ov);
      } else {
        ((bf16*)outbase)[lND + off] = f2bf(ov);
      }
    }
}

// ---------------- launch ----------------

extern "C" void kernel_launch(void* const* d_in, const int* in_sizes, int n_in, void* d_out,
                              int out_size, void* d_ws, size_t ws_size, hipStream_t stream) {
  const void* x = d_in[0];
  const void* h = d_in[1];
  const void* Wl = d_in[2];
  const void* Wr = d_in[3];
  const void* b = d_in[4];
  const int* src = (const int*)d_in[5];
  const int* dst = (const int*)d_in[6];

  const int NX = in_sizes[0];
  const int NH = in_sizes[1];
  const int N = NX / D;
  const int E = in_sizes[5];
  const int L = NH / NX;
  (void)n_in;
  (void)out_size;
  (void)ws_size;

  char* ws = (char*)d_ws;
  size_t off = 0;
  auto alloc = [&](size_t bytes) -> char* {
    char* p = ws + off;
    off = (off + bytes + 255) & ~(size_t)255;
    return p;
  };
  int* flag = (int*)alloc(256);
  int* deg = (int*)alloc((size_t)N * 4);
  int* offs = (int*)alloc((size_t)(N + 1) * 4);
  int* cursor = (int*)alloc((size_t)N * 4);
  float* inv_deg = (float*)alloc((size_t)N * 4);
  int* bsum = (int*)alloc(256 * 4);
  int* esrc = (int*)alloc((size_t)E * 4);
  bf16* agg_inp = (bf16*)alloc((size_t)N * D * 2);
  bf16* agg2 = (bf16*)alloc((size_t)N * D * 2);
  bf16* rh = (bf16*)alloc((size_t)N * D * 2);
  __half* z = (__half*)alloc((size_t)N * D * 2);
  bf16* B1p = (bf16*)alloc((size_t)L * PACK_SZ1 * 2);
  bf16* B2p = (bf16*)alloc((size_t)L * PACK_SZ2 * 2);
  float* bs1 = (float*)alloc((size_t)L * 256 * 4);
  float* bs2 = (float*)alloc((size_t)L * 128 * 4);
  bf16* xb = (bf16*)alloc((size_t)NX * 2);  // fp32 mode only
  bf16* hb = (bf16*)alloc((size_t)NH * 2);  // fp32 mode only

  probe_kernel<<<1, 256, 0, stream>>>((const unsigned short*)Wl, in_sizes[2], flag);
  int ncv = NX > NH ? NX : NH;
  convert_kernel<<<(ncv / 4 + 255) / 256, 256, 0, stream>>>((const float*)x, (const float*)h, xb,
                                                            hb, flag, NX, NH);
  pack_kernel<<<(L * PACK_P + 255) / 256, 256, 0, stream>>>(Wl, Wr, b, L, flag, B1p, B2p, bs1,
                                                            bs2);

  zero_int_kernel<<<(N + 255) / 256, 256, 0, stream>>>(deg, N);
  count_deg_kernel<<<(E + 255) / 256, 256, 0, stream>>>(dst, deg, E);
  int nb = (N + SCAN_BLK - 1) / SCAN_BLK;  // 49 for N=50000; scan2 handles nb<=256
  scan1_kernel<<<nb, 256, 0, stream>>>(deg, bsum, N);
  scan2_kernel<<<1, 256, 0, stream>>>(bsum, nb);
  scan3_kernel<<<nb, 256, 0, stream>>>(deg, bsum, offs, cursor, inv_deg, N, E);
  scatter_kernel<<<(E + 255) / 256, 256, 0, stream>>>(src, dst, cursor, esrc, E);

  int mtiles = (N + BM - 1) / BM;
  for (int l = 0; l < L; ++l) {
    const size_t lND = (size_t)l * N * D;
    const bf16* inpA = (l == 0) ? (const bf16*)x : ((const bf16*)d_out + lND - (size_t)N * D);
    const bf16* hlA = (const bf16*)h + lND;
    const bf16* hlB = hb + lND;
    const bf16* B1l = B1p + (size_t)l * PACK_SZ1;
    const bf16* B2l = B2p + (size_t)l * PACK_SZ2;
    const float* bs1l = bs1 + (size_t)l * 256;
    const float* bs2l = bs2 + (size_t)l * 128;

    agg_dual_kernel<<<(N + 3) / 4, 256, 0, stream>>>(inpA, xb, hlA, hlB, flag, esrc, offs, inv_deg,
                                                     agg_inp, agg2, N);
    gemm1_kernel<<<dim3(mtiles, 2), 256, 0, stream>>>(agg_inp, inpA, xb, agg2, hlA, hlB, flag, B1l,
                                                      bs1l, z, rh, N);
    agg_kernel<<<(N + 3) / 4, 256, 0, stream>>>(rh, rh, flag, esrc, offs, inv_deg, agg2, N);
    gemm2_kernel<<<dim3(mtiles, 1), 256, 0, stream>>>(agg_inp, inpA, xb, agg2, rh, hlA, hlB, flag,
                                                      B2l, bs2l, z, d_out, lND,
                                                      (l + 1 < L) ? xb : (bf16*)nullptr, N);
  }
}